// Round 14
// baseline (218.544 us; speedup 1.0000x reference)
//
#include <hip/hip_runtime.h>
#include <math.h>

// Problem constants: B=2, C=256, DM=512, H=8, D=64, SPARSE_K=64
typedef _Float16 fp16;
typedef __attribute__((ext_vector_type(4))) _Float16 f16x4;
typedef __attribute__((ext_vector_type(8))) _Float16 f16x8;
typedef __attribute__((ext_vector_type(4))) float floatx4;
typedef __attribute__((ext_vector_type(2))) float f32x2;

__device__ __forceinline__ f32x2 mk2(float a, float b) { f32x2 r; r.x = a; r.y = b; return r; }
__device__ __forceinline__ f32x2 sp2(float a) { f32x2 r; r.x = a; r.y = a; return r; }

// ---------------------------------------------------------------------------
// Packed-pair gelu (R1/R7-proven v_pk_fma_f32 lowering): 6-term Taylor erf on
// |t|<=0.5 (abs err <= 1.5e-8), erff fallback for rare outliers.
// ---------------------------------------------------------------------------
__device__ __forceinline__ f32x2 gelu2(f32x2 x) {
    f32x2 tt = x * 0.70710678118654752440f;
    f32x2 s  = tt * tt;
    f32x2 p  = __builtin_elementwise_fma(s, sp2(-8.548327023450852e-4f), sp2(5.223977625442188e-3f));
    p = __builtin_elementwise_fma(s, p, sp2(-2.6866170645131252e-2f));
    p = __builtin_elementwise_fma(s, p, sp2(0.11283791670955126f));
    p = __builtin_elementwise_fma(s, p, sp2(-0.3761263890318375f));
    p = __builtin_elementwise_fma(s, p, sp2(1.1283791670955126f));
    f32x2 e = tt * p;
    if (__builtin_expect(fabsf(tt.x) > 0.5f, 0)) e.x = erff(tt.x);
    if (__builtin_expect(fabsf(tt.y) > 0.5f, 0)) e.y = erff(tt.y);
    f32x2 hx = x * 0.5f;
    return __builtin_elementwise_fma(hx, e, hx);   // 0.5x + 0.5x*e
}

// ---------------------------------------------------------------------------
// fp16 DUAL split: h = fp16(x), m = fp16(x - h). ~22 mantissa bits; fp16*fp16
// products are EXACT in the fp32 MFMA accumulator (R5-verified). The mm
// (Am*Km) cross-product is dropped everywhere (R13-verified: absmax
// unchanged at 2.44e-4) — it contributes O(2^-22) relative.
// ---------------------------------------------------------------------------
__device__ __forceinline__ void split2(float a, fp16& h, fp16& m) {
    h = (fp16)a;
    m = (fp16)(a - (float)h);
}

// ---------------------------------------------------------------------------
// Dual-split into MFMA frag-major order for [512][512] matrices; 5 matrices
// batched via blockIdx.z. (row,k) -> ((rt*16+ks)*64 + q4*16 + rm)*8 + u.
// ---------------------------------------------------------------------------
struct SplitArgs {
    const float* src[5];
    fp16* h[5]; fp16* m[5];
};

__global__ __launch_bounds__(256) void split2_512_kernel(SplitArgs S) {
    int z = blockIdx.z;
    const float* src = S.src[z];
    fp16* dh = S.h[z]; fp16* dm = S.m[z];
    int t = blockIdx.x * 256 + threadIdx.x;
    int row = t >> 7, kq = (t & 127) * 4;
    int rt = row >> 4, rm = row & 15;
    int ks = kq >> 5, q4 = (kq >> 3) & 3, u0 = kq & 7;
    int dst = ((rt * 16 + ks) * 64 + q4 * 16 + rm) * 8 + u0;
    float4 vv = *(const float4*)&src[row * 512 + kq];
    float a4[4] = {vv.x, vv.y, vv.z, vv.w};
    f16x4 h, m;
    #pragma unroll
    for (int u = 0; u < 4; u++) {
        fp16 hh, mm;
        split2(a4[u], hh, mm);
        h[u] = hh; m[u] = mm;
    }
    *(f16x4*)&dh[dst] = h;
    *(f16x4*)&dm[dst] = m;
}

// ---------------------------------------------------------------------------
// C = A @ W^T + bias via dual-split fp16 MFMA. 3 MFMAs per k-step
// (hh + mh in acc0; hm in acc1; mm dropped). mode 0: fp32 [m*512+n];
// mode 1: heads fp32 (b,h,c,d); mode 2: K written as frag-major dual-split.
// ---------------------------------------------------------------------------
struct MM2Args {
    const fp16 *Ah, *Am;
    const fp16 *Wh[3], *Wm[3];
    const float* bias[3];
    float* outf[3];
    fp16 *kh, *km;
    int mode[3];
};

__global__ __launch_bounds__(64) void mm_mfma_kernel(MM2Args A) {
    const int z = blockIdx.z;
    const fp16* Wh = A.Wh[z]; const fp16* Wm = A.Wm[z];
    const float* bias = A.bias[z];
    const int lane = threadIdx.x;
    const int m16 = lane & 15, q4 = lane >> 4;
    const int mt = blockIdx.y, bx = blockIdx.x;

    floatx4 acc0, acc1;
    {
        float bv = bias[bx * 16 + m16];
        acc0[0] = bv; acc0[1] = bv; acc0[2] = bv; acc0[3] = bv;
        acc1[0] = 0.f; acc1[1] = 0.f; acc1[2] = 0.f; acc1[3] = 0.f;
    }

    #pragma unroll 4
    for (int ks = 0; ks < 16; ks++) {
        int sa = ((mt * 16 + ks) * 64 + lane) * 8;
        f16x8 ah = *(const f16x8*)&A.Ah[sa];
        f16x8 am = *(const f16x8*)&A.Am[sa];
        int sw = ((bx * 16 + ks) * 64 + lane) * 8;
        f16x8 wh = *(const f16x8*)&Wh[sw];
        f16x8 wm = *(const f16x8*)&Wm[sw];
        acc0 = __builtin_amdgcn_mfma_f32_16x16x32_f16(ah, wh, acc0, 0, 0, 0);
        acc1 = __builtin_amdgcn_mfma_f32_16x16x32_f16(ah, wm, acc1, 0, 0, 0);
        acc0 = __builtin_amdgcn_mfma_f32_16x16x32_f16(am, wh, acc0, 0, 0, 0);
    }
    floatx4 acc = acc0 + acc1;

    const int mode = A.mode[z];
    const int n = bx * 16 + m16;
    #pragma unroll
    for (int r = 0; r < 4; r++) {
        int m = mt * 16 + q4 * 4 + r;
        float val = acc[r];
        if (mode == 0) {
            A.outf[z][m * 512 + n] = val;
        } else if (mode == 1) {
            A.outf[z][(((m >> 8) * 8 + (n >> 6)) * 256 + (m & 255)) * 64 + (n & 63)] = val;
        } else {
            int krow = ((m >> 8) * 8 + (n >> 6)) * 256 + (m & 255);
            int d = n & 63;
            int dst = (((krow >> 4) * 2 + (d >> 5)) * 64 + ((d >> 3) & 3) * 16 + (krow & 15)) * 8 + (d & 7);
            fp16 h, mm;
            split2(val, h, mm);
            A.kh[dst] = h; A.km[dst] = mm;
        }
    }
}

// ---------------------------------------------------------------------------
// R14 kernel S — scores only. Post-mortems: R12 (in-loop loads, 48 VGPR) ->
// occ 43%, 60.7us; R13 (+prefetch, 56 VGPR) -> occ 35%, 59.1us: prefetch
// is net-negative (regs cost residency; loads were already covered at 3.4
// waves). Issue accounting: VALU-bound floor ~23us, we're at 59 -> stall-
// dominated. Resources permit 8 waves/SIMD (VGPR 48 <= 64, LDS 8.7KB,
// exactly 8 blocks/CU of work) — request it: __launch_bounds__(256,8).
// Unlike R2 (monolith needed ~150 regs, cap forced 90 regs of spill), this
// kernel ALREADY fits the 64-reg/8-wave regime; the hint is free.
// 12 MFMAs/jt (mm term dropped), in-loop K loads.
// ---------------------------------------------------------------------------
__global__ __launch_bounds__(256, 8) void score_kernel(
    const float* __restrict__ q,
    const fp16* __restrict__ khi, const fp16* __restrict__ kmid,
    const float* __restrict__ w1, const float* __restrict__ b1,
    const float* __restrict__ w2, const float* __restrict__ b2,
    float* __restrict__ scores)
{
    const int i2 = blockIdx.x;     // query pair: i = 2*i2 + i01
    const int bh = blockIdx.y;
    const int t  = threadIdx.x;
    const int lane = t & 63, w = t >> 6;
    const int m16 = lane & 15, q4 = lane >> 4;

    __shared__ f32x2 part2[4][256];
    __shared__ float qpb_s[2][64];

    const int f = w * 16 + m16;
    const float* w1row = w1 + f * 192;
    const float4 w2f = *(const float4*)&w2[w * 16 + q4 * 4];
    const float b2v = b2[0];
    const float* qbase = q + (bh * 256 + i2 * 2) * 64;

    // ---- build A frags (2 queries) + qpb
    f16x8 Ah[2][2], Am[2][2];
    float qa0 = 0.f, qa1 = 0.f;
    #pragma unroll
    for (int ks = 0; ks < 2; ks++) {
        #pragma unroll
        for (int u = 0; u < 2; u++) {
            int e = ks * 32 + q4 * 8 + u * 4;
            float4 wa = *(const float4*)&w1row[e];
            float4 wb = *(const float4*)&w1row[64 + e];
            float4 wc = *(const float4*)&w1row[128 + e];
            #pragma unroll
            for (int i01 = 0; i01 < 2; i01++) {
                float4 qv = *(const float4*)&qbase[i01 * 64 + e];
                float dq = wa.x * qv.x + wa.y * qv.y + wa.z * qv.z + wa.w * qv.w;
                if (i01 == 0) qa0 += dq; else qa1 += dq;
                float av[4];
                av[0] = fmaf(wc.x, qv.x, wb.x);
                av[1] = fmaf(wc.y, qv.y, wb.y);
                av[2] = fmaf(wc.z, qv.z, wb.z);
                av[3] = fmaf(wc.w, qv.w, wb.w);
                #pragma unroll
                for (int uu = 0; uu < 4; uu++) {
                    fp16 h, m;
                    split2(av[uu], h, m);
                    Ah[i01][ks][u * 4 + uu] = h;
                    Am[i01][ks][u * 4 + uu] = m;
                }
            }
        }
    }
    qa0 += __shfl_xor(qa0, 16);
    qa0 += __shfl_xor(qa0, 32);
    qa1 += __shfl_xor(qa1, 16);
    qa1 += __shfl_xor(qa1, 32);
    if (lane < 16) {
        qpb_s[0][w * 16 + lane] = qa0 + b1[w * 16 + lane];
        qpb_s[1][w * 16 + lane] = qa1 + b1[w * 16 + lane];
    }
    __syncthreads();

    floatx4 qpbr0 = *(const floatx4*)&qpb_s[0][w * 16 + q4 * 4];
    floatx4 qpbr1 = *(const floatx4*)&qpb_s[1][w * 16 + q4 * 4];

    // ---- jt loop: in-loop K loads (TLP covers), 12 MFMAs as 4 chains
    #pragma unroll 1
    for (int jt = 0; jt < 16; jt++) {
        int base = ((bh * 16 + jt) * 2 * 64 + lane) * 8;
        f16x8 Kh0 = *(const f16x8*)&khi [base];
        f16x8 Km0 = *(const f16x8*)&kmid[base];
        f16x8 Kh1 = *(const f16x8*)&khi [base + 512];
        f16x8 Km1 = *(const f16x8*)&kmid[base + 512];
        floatx4 a0 = qpbr0, a1 = qpbr1;
        floatx4 b0, b1v_;
        b0[0] = 0.f; b0[1] = 0.f; b0[2] = 0.f; b0[3] = 0.f;
        b1v_ = b0;
        // 12 MFMAs: per query a-chain {hh0,mh0,hh1,mh1}, b-chain {hm0,hm1}
        a0   = __builtin_amdgcn_mfma_f32_16x16x32_f16(Ah[0][0], Kh0, a0,   0, 0, 0);
        a1   = __builtin_amdgcn_mfma_f32_16x16x32_f16(Ah[1][0], Kh0, a1,   0, 0, 0);
        b0   = __builtin_amdgcn_mfma_f32_16x16x32_f16(Ah[0][0], Km0, b0,   0, 0, 0);
        b1v_ = __builtin_amdgcn_mfma_f32_16x16x32_f16(Ah[1][0], Km0, b1v_, 0, 0, 0);
        a0   = __builtin_amdgcn_mfma_f32_16x16x32_f16(Am[0][0], Kh0, a0,   0, 0, 0);
        a1   = __builtin_amdgcn_mfma_f32_16x16x32_f16(Am[1][0], Kh0, a1,   0, 0, 0);
        b0   = __builtin_amdgcn_mfma_f32_16x16x32_f16(Ah[0][1], Km1, b0,   0, 0, 0);
        b1v_ = __builtin_amdgcn_mfma_f32_16x16x32_f16(Ah[1][1], Km1, b1v_, 0, 0, 0);
        a0   = __builtin_amdgcn_mfma_f32_16x16x32_f16(Ah[0][1], Kh1, a0,   0, 0, 0);
        a1   = __builtin_amdgcn_mfma_f32_16x16x32_f16(Ah[1][1], Kh1, a1,   0, 0, 0);
        a0   = __builtin_amdgcn_mfma_f32_16x16x32_f16(Am[0][1], Kh1, a0,   0, 0, 0);
        a1   = __builtin_amdgcn_mfma_f32_16x16x32_f16(Am[1][1], Kh1, a1,   0, 0, 0);
        a0 = a0 + b0; a1 = a1 + b1v_;
        // packed epilogue
        f32x2 g0 = gelu2(mk2(a0[0], a1[0]));
        f32x2 g1 = gelu2(mk2(a0[1], a1[1]));
        f32x2 g2 = gelu2(mk2(a0[2], a1[2]));
        f32x2 g3 = gelu2(mk2(a0[3], a1[3]));
        f32x2 sA = __builtin_elementwise_fma(g1, sp2(w2f.y), g0 * w2f.x);
        f32x2 sB = __builtin_elementwise_fma(g3, sp2(w2f.w), g2 * w2f.z);
        f32x2 s = sA + sB;
        s.x += __shfl_xor(s.x, 16);
        s.y += __shfl_xor(s.y, 16);
        s.x += __shfl_xor(s.x, 32);
        s.y += __shfl_xor(s.y, 32);
        if (lane < 16) part2[w][jt * 16 + lane] = s;
    }
    __syncthreads();

    // ---- final scores for j = t, both queries; coalesced store
    f32x2 sc = ((part2[0][t] + part2[1][t]) +
                (part2[2][t] + part2[3][t]) + b2v) * 0.125f;
    scores[(bh * 256 + i2 * 2 + 0) * 256 + t] = sc.x;
    scores[(bh * 256 + i2 * 2 + 1) * 256 + t] = sc.y;
}

// ---------------------------------------------------------------------------
// Kernel T — top-64 + softmax + attn@V + output for an i-quad. No MFMA,
// register-light, 1024 blocks. Verbatim from R12 (not in top-5 cost).
// ---------------------------------------------------------------------------
__global__ __launch_bounds__(256, 4) void topk_attn_kernel(
    const float* __restrict__ scores, const float* __restrict__ v,
    fp16* __restrict__ oh, fp16* __restrict__ om)
{
    const int i4 = blockIdx.x;     // query quad: i = 4*i4 + i01
    const int bh = blockIdx.y;
    const int t  = threadIdx.x;
    const int lane = t & 63, w = t >> 6;

    __shared__ f32x2 sc2[2][256];       // softmax probabilities, 2 pairs
    __shared__ f32x2 sbuf2[2][256];     // bitonic cross-wave exchange
    __shared__ f32x2 red_s[2][4][64];   // attn@V partials
    __shared__ f32x2 red2_s[2][4];
    __shared__ f32x2 thr_s2[2], smax_s2[2];

    // ---- load scores for the 4 queries (coalesced: thread t reads j=t)
    const float* sb = scores + (bh * 256 + i4 * 4) * 256;
    f32x2 score0 = mk2(sb[t], sb[256 + t]);
    f32x2 score1 = mk2(sb[512 + t], sb[768 + t]);

    // ---- quad lockstep 256-wide bitonic sort; sorted[192] = 64th largest.
    f32x2 sv0 = score0, sv1 = score1;
    #pragma unroll
    for (int k = 2; k <= 256; k <<= 1) {
        #pragma unroll
        for (int j = k >> 1; j >= 1; j >>= 1) {
            f32x2 pv0, pv1;
            if (j >= 64) {
                sbuf2[0][t] = sv0; sbuf2[1][t] = sv1;
                __syncthreads();
                pv0 = sbuf2[0][t ^ j]; pv1 = sbuf2[1][t ^ j];
                __syncthreads();
            } else {
                pv0.x = __shfl_xor(sv0.x, j);
                pv0.y = __shfl_xor(sv0.y, j);
                pv1.x = __shfl_xor(sv1.x, j);
                pv1.y = __shfl_xor(sv1.y, j);
            }
            bool keepMin = (((t & j) == 0) == ((t & k) == 0));
            f32x2 mn0 = __builtin_elementwise_min(sv0, pv0);
            f32x2 mx0 = __builtin_elementwise_max(sv0, pv0);
            f32x2 mn1 = __builtin_elementwise_min(sv1, pv1);
            f32x2 mx1 = __builtin_elementwise_max(sv1, pv1);
            sv0 = keepMin ? mn0 : mx0;
            sv1 = keepMin ? mn1 : mx1;
        }
    }
    if (t == 192) { thr_s2[0]  = sv0; thr_s2[1]  = sv1; }
    if (t == 255) { smax_s2[0] = sv0; smax_s2[1] = sv1; }
    __syncthreads();

    // ---- softmax numerator + denominator (two packed pairs)
    float p00 = (score0.x >= thr_s2[0].x) ? __expf(score0.x - smax_s2[0].x) : 0.0f;
    float p01 = (score0.y >= thr_s2[0].y) ? __expf(score0.y - smax_s2[0].y) : 0.0f;
    float p10 = (score1.x >= thr_s2[1].x) ? __expf(score1.x - smax_s2[1].x) : 0.0f;
    float p11 = (score1.y >= thr_s2[1].y) ? __expf(score1.y - smax_s2[1].y) : 0.0f;
    sc2[0][t] = mk2(p00, p01);
    sc2[1][t] = mk2(p10, p11);
    f32x2 ps0 = mk2(p00, p01), ps1 = mk2(p10, p11);
    #pragma unroll
    for (int mask = 1; mask < 64; mask <<= 1) {
        ps0.x += __shfl_xor(ps0.x, mask);
        ps0.y += __shfl_xor(ps0.y, mask);
        ps1.x += __shfl_xor(ps1.x, mask);
        ps1.y += __shfl_xor(ps1.y, mask);
    }
    if (lane == 0) { red2_s[0][w] = ps0; red2_s[1][w] = ps1; }
    __syncthreads();
    f32x2 den0 = (red2_s[0][0] + red2_s[0][1]) + (red2_s[0][2] + red2_s[0][3]);
    f32x2 den1 = (red2_s[1][0] + red2_s[1][1]) + (red2_s[1][2] + red2_s[1][3]);
    f32x2 invp0 = mk2(1.0f / den0.x, 1.0f / den0.y);
    f32x2 invp1 = mk2(1.0f / den1.x, 1.0f / den1.y);

    // ---- attn @ V: V loads shared across all 4 queries, x2 unroll
    const int d = t & 63, g = t >> 6;
    const float* vb = v + bh * 256 * 64;
    f32x2 av0 = mk2(0.f, 0.f), av1 = mk2(0.f, 0.f);
    f32x2 av0b = mk2(0.f, 0.f), av1b = mk2(0.f, 0.f);
    for (int j8 = 0; j8 < 8; j8++) {
        int jj = g * 64 + j8 * 8;
        float v0 = vb[(jj + 0) * 64 + d];
        float v1 = vb[(jj + 1) * 64 + d];
        float v2 = vb[(jj + 2) * 64 + d];
        float v3 = vb[(jj + 3) * 64 + d];
        float v4 = vb[(jj + 4) * 64 + d];
        float v5 = vb[(jj + 5) * 64 + d];
        float v6 = vb[(jj + 6) * 64 + d];
        float v7 = vb[(jj + 7) * 64 + d];
        av0  = __builtin_elementwise_fma(sc2[0][jj + 0], sp2(v0), av0);
        av1  = __builtin_elementwise_fma(sc2[1][jj + 0], sp2(v0), av1);
        av0b = __builtin_elementwise_fma(sc2[0][jj + 4], sp2(v4), av0b);
        av1b = __builtin_elementwise_fma(sc2[1][jj + 4], sp2(v4), av1b);
        av0  = __builtin_elementwise_fma(sc2[0][jj + 1], sp2(v1), av0);
        av1  = __builtin_elementwise_fma(sc2[1][jj + 1], sp2(v1), av1);
        av0b = __builtin_elementwise_fma(sc2[0][jj + 5], sp2(v5), av0b);
        av1b = __builtin_elementwise_fma(sc2[1][jj + 5], sp2(v5), av1b);
        av0  = __builtin_elementwise_fma(sc2[0][jj + 2], sp2(v2), av0);
        av1  = __builtin_elementwise_fma(sc2[1][jj + 2], sp2(v2), av1);
        av0b = __builtin_elementwise_fma(sc2[0][jj + 6], sp2(v6), av0b);
        av1b = __builtin_elementwise_fma(sc2[1][jj + 6], sp2(v6), av1b);
        av0  = __builtin_elementwise_fma(sc2[0][jj + 3], sp2(v3), av0);
        av1  = __builtin_elementwise_fma(sc2[1][jj + 3], sp2(v3), av1);
        av0b = __builtin_elementwise_fma(sc2[0][jj + 7], sp2(v7), av0b);
        av1b = __builtin_elementwise_fma(sc2[1][jj + 7], sp2(v7), av1b);
    }
    red_s[0][g][d] = av0 + av0b;
    red_s[1][g][d] = av1 + av1b;
    __syncthreads();

    // ---- output: all 256 threads write one (i01, dd) each
    {
        int i01 = t >> 6, dd = t & 63;
        int pr = i01 >> 1, comp = i01 & 1;
        f32x2 osum = (red_s[pr][0][dd] + red_s[pr][1][dd]) +
                     (red_s[pr][2][dd] + red_s[pr][3][dd]);
        f32x2 iv = pr ? invp1 : invp0;
        float o = (comp ? osum.y : osum.x) * (comp ? iv.y : iv.x);
        int b = bh >> 3, h = bh & 7;
        int row = b * 256 + i4 * 4 + i01;
        int n = h * 64 + dd;
        int dst = (((row >> 4) * 16 + (n >> 5)) * 64 + ((n >> 3) & 3) * 16 + (row & 15)) * 8 + (n & 7);
        fp16 hh, mm;
        split2(o, hh, mm);
        oh[dst] = hh; om[dst] = mm;
    }
}

// ---------------------------------------------------------------------------
extern "C" void kernel_launch(void* const* d_in, const int* in_sizes, int n_in,
                              void* d_out, int out_size, void* d_ws, size_t ws_size,
                              hipStream_t stream) {
    const float* x  = (const float*)d_in[0];
    const float* Wq = (const float*)d_in[1];
    const float* bq = (const float*)d_in[2];
    const float* Wk = (const float*)d_in[3];
    const float* bk = (const float*)d_in[4];
    const float* Wv = (const float*)d_in[5];
    const float* bv = (const float*)d_in[6];
    const float* w1 = (const float*)d_in[7];
    const float* b1 = (const float*)d_in[8];
    const float* w2 = (const float*)d_in[9];
    const float* b2 = (const float*)d_in[10];
    const float* Wo = (const float*)d_in[11];
    const float* bo = (const float*)d_in[12];
    float* out = (float*)d_out;

    const int NE = 262144;   // 512*512
    float* qb  = (float*)d_ws;          // q (b,h,c,d) fp32
    float* vb  = qb + NE;               // v (b,h,c,d) fp32
    fp16* base = (fp16*)(vb + NE);
    fp16* khi  = base;            fp16* kmid = khi + NE;
    fp16* xs   = kmid + NE;       // hi/mid duals follow (2*NE each)
    fp16* wqs  = xs  + 2 * NE;
    fp16* wks  = wqs + 2 * NE;
    fp16* wvs  = wks + 2 * NE;
    fp16* wos  = wvs + 2 * NE;
    fp16* oas  = wos + 2 * NE;
    // scores (16*256*256 fp32 = 4MB) ALIASES xs..wvs (4MB of fp16 duals) —
    // those are dead after the QKV mm completes, before score_kernel runs.
    float* scores = (float*)xs;

    // 1) split x, Wq, Wk, Wv, Wo into frag-major fp16 duals
    {
        SplitArgs S;
        const float* srcs[5] = {x, Wq, Wk, Wv, Wo};
        fp16* dsts[5] = {xs, wqs, wks, wvs, wos};
        for (int z = 0; z < 5; z++) {
            S.src[z] = srcs[z];
            S.h[z] = dsts[z]; S.m[z] = dsts[z] + NE;
        }
        split2_512_kernel<<<dim3(256, 1, 5), 256, 0, stream>>>(S);
    }
    // 2) QKV projections; K written directly as dual-split frag-major
    {
        MM2Args M;
        M.Ah = xs; M.Am = xs + NE;
        M.Wh[0] = wqs; M.Wm[0] = wqs + NE;
        M.Wh[1] = wks; M.Wm[1] = wks + NE;
        M.Wh[2] = wvs; M.Wm[2] = wvs + NE;
        M.bias[0] = bq; M.bias[1] = bk; M.bias[2] = bv;
        M.outf[0] = qb; M.outf[1] = nullptr; M.outf[2] = vb;
        M.kh = khi; M.km = kmid;
        M.mode[0] = 1; M.mode[1] = 2; M.mode[2] = 1;
        mm_mfma_kernel<<<dim3(32, 32, 3), 64, 0, stream>>>(M);
    }
    // 3a) second-order scores (MFMA-shaped kernel, 8-wave residency)
    score_kernel<<<dim3(128, 16), 256, 0, stream>>>(
        qb, khi, kmid, w1, b1, w2, b2, scores);
    // 3b) top-64 + softmax + attn@V + dual-split output (register-light)
    topk_attn_kernel<<<dim3(64, 16), 256, 0, stream>>>(
        scores, vb, oas, oas + NE);
    // 4) output projection
    {
        MM2Args M;
        M.Ah = oas; M.Am = oas + NE;
        M.Wh[0] = wos; M.Wm[0] = wos + NE;
        M.Wh[1] = wos; M.Wm[1] = wos;
        M.Wh[2] = wos; M.Wm[2] = wos;
        M.bias[0] = bo; M.bias[1] = bo; M.bias[2] = bo;
        M.outf[0] = out; M.outf[1] = out; M.outf[2] = out;
        M.kh = khi; M.km = kmid;
        M.mode[0] = 0; M.mode[1] = 0; M.mode[2] = 0;
        mm_mfma_kernel<<<dim3(32, 32, 1), 64, 0, stream>>>(M);
    }
}

// Round 15
// 158.120 us; speedup vs baseline: 1.3821x; 1.3821x over previous
//
#include <hip/hip_runtime.h>
#include <math.h>

// Problem constants: B=2, C=256, DM=512, H=8, D=64, SPARSE_K=64
typedef _Float16 fp16;
typedef __attribute__((ext_vector_type(4))) _Float16 f16x4;
typedef __attribute__((ext_vector_type(8))) _Float16 f16x8;
typedef __attribute__((ext_vector_type(4))) float floatx4;
typedef __attribute__((ext_vector_type(2))) float f32x2;

__device__ __forceinline__ f32x2 mk2(float a, float b) { f32x2 r; r.x = a; r.y = b; return r; }
__device__ __forceinline__ f32x2 sp2(float a) { f32x2 r; r.x = a; r.y = a; return r; }

// ---------------------------------------------------------------------------
// Packed-pair gelu (R1/R7-proven v_pk_fma_f32 lowering): 6-term Taylor erf on
// |t|<=0.5 (abs err <= 1.5e-8), erff fallback for rare outliers.
// ---------------------------------------------------------------------------
__device__ __forceinline__ f32x2 gelu2(f32x2 x) {
    f32x2 tt = x * 0.70710678118654752440f;
    f32x2 s  = tt * tt;
    f32x2 p  = __builtin_elementwise_fma(s, sp2(-8.548327023450852e-4f), sp2(5.223977625442188e-3f));
    p = __builtin_elementwise_fma(s, p, sp2(-2.6866170645131252e-2f));
    p = __builtin_elementwise_fma(s, p, sp2(0.11283791670955126f));
    p = __builtin_elementwise_fma(s, p, sp2(-0.3761263890318375f));
    p = __builtin_elementwise_fma(s, p, sp2(1.1283791670955126f));
    f32x2 e = tt * p;
    if (__builtin_expect(fabsf(tt.x) > 0.5f, 0)) e.x = erff(tt.x);
    if (__builtin_expect(fabsf(tt.y) > 0.5f, 0)) e.y = erff(tt.y);
    f32x2 hx = x * 0.5f;
    return __builtin_elementwise_fma(hx, e, hx);   // 0.5x + 0.5x*e
}

// ---------------------------------------------------------------------------
// fp16 DUAL split: h = fp16(x), m = fp16(x - h). ~22 mantissa bits; fp16*fp16
// products are EXACT in the fp32 MFMA accumulator (R5-verified). The mm
// (Am*Km) cross-product is dropped everywhere (R13/R14-verified: absmax
// bit-identical at 2.44e-4) — it contributes O(2^-22) relative.
// ---------------------------------------------------------------------------
__device__ __forceinline__ void split2(float a, fp16& h, fp16& m) {
    h = (fp16)a;
    m = (fp16)(a - (float)h);
}

// ---------------------------------------------------------------------------
// Dual-split into MFMA frag-major order for [512][512] matrices; 5 matrices
// batched via blockIdx.z. (row,k) -> ((rt*16+ks)*64 + q4*16 + rm)*8 + u.
// ---------------------------------------------------------------------------
struct SplitArgs {
    const float* src[5];
    fp16* h[5]; fp16* m[5];
};

__global__ __launch_bounds__(256) void split2_512_kernel(SplitArgs S) {
    int z = blockIdx.z;
    const float* src = S.src[z];
    fp16* dh = S.h[z]; fp16* dm = S.m[z];
    int t = blockIdx.x * 256 + threadIdx.x;
    int row = t >> 7, kq = (t & 127) * 4;
    int rt = row >> 4, rm = row & 15;
    int ks = kq >> 5, q4 = (kq >> 3) & 3, u0 = kq & 7;
    int dst = ((rt * 16 + ks) * 64 + q4 * 16 + rm) * 8 + u0;
    float4 vv = *(const float4*)&src[row * 512 + kq];
    float a4[4] = {vv.x, vv.y, vv.z, vv.w};
    f16x4 h, m;
    #pragma unroll
    for (int u = 0; u < 4; u++) {
        fp16 hh, mm;
        split2(a4[u], hh, mm);
        h[u] = hh; m[u] = mm;
    }
    *(f16x4*)&dh[dst] = h;
    *(f16x4*)&dm[dst] = m;
}

// ---------------------------------------------------------------------------
// C = A @ W^T + bias via dual-split fp16 MFMA. 3 MFMAs per k-step
// (hh + mh in acc0; hm in acc1; mm dropped). mode 0: fp32 [m*512+n];
// mode 1: heads fp32 (b,h,c,d); mode 2: K written as frag-major dual-split.
// ---------------------------------------------------------------------------
struct MM2Args {
    const fp16 *Ah, *Am;
    const fp16 *Wh[3], *Wm[3];
    const float* bias[3];
    float* outf[3];
    fp16 *kh, *km;
    int mode[3];
};

__global__ __launch_bounds__(64) void mm_mfma_kernel(MM2Args A) {
    const int z = blockIdx.z;
    const fp16* Wh = A.Wh[z]; const fp16* Wm = A.Wm[z];
    const float* bias = A.bias[z];
    const int lane = threadIdx.x;
    const int m16 = lane & 15, q4 = lane >> 4;
    const int mt = blockIdx.y, bx = blockIdx.x;

    floatx4 acc0, acc1;
    {
        float bv = bias[bx * 16 + m16];
        acc0[0] = bv; acc0[1] = bv; acc0[2] = bv; acc0[3] = bv;
        acc1[0] = 0.f; acc1[1] = 0.f; acc1[2] = 0.f; acc1[3] = 0.f;
    }

    #pragma unroll 4
    for (int ks = 0; ks < 16; ks++) {
        int sa = ((mt * 16 + ks) * 64 + lane) * 8;
        f16x8 ah = *(const f16x8*)&A.Ah[sa];
        f16x8 am = *(const f16x8*)&A.Am[sa];
        int sw = ((bx * 16 + ks) * 64 + lane) * 8;
        f16x8 wh = *(const f16x8*)&Wh[sw];
        f16x8 wm = *(const f16x8*)&Wm[sw];
        acc0 = __builtin_amdgcn_mfma_f32_16x16x32_f16(ah, wh, acc0, 0, 0, 0);
        acc1 = __builtin_amdgcn_mfma_f32_16x16x32_f16(ah, wm, acc1, 0, 0, 0);
        acc0 = __builtin_amdgcn_mfma_f32_16x16x32_f16(am, wh, acc0, 0, 0, 0);
    }
    floatx4 acc = acc0 + acc1;

    const int mode = A.mode[z];
    const int n = bx * 16 + m16;
    #pragma unroll
    for (int r = 0; r < 4; r++) {
        int m = mt * 16 + q4 * 4 + r;
        float val = acc[r];
        if (mode == 0) {
            A.outf[z][m * 512 + n] = val;
        } else if (mode == 1) {
            A.outf[z][(((m >> 8) * 8 + (n >> 6)) * 256 + (m & 255)) * 64 + (n & 63)] = val;
        } else {
            int krow = ((m >> 8) * 8 + (n >> 6)) * 256 + (m & 255);
            int d = n & 63;
            int dst = (((krow >> 4) * 2 + (d >> 5)) * 64 + ((d >> 3) & 3) * 16 + (krow & 15)) * 8 + (d & 7);
            fp16 h, mm;
            split2(val, h, mm);
            A.kh[dst] = h; A.km[dst] = mm;
        }
    }
}

// ---------------------------------------------------------------------------
// R15 fused kernel = R9 (best measured: fused 72.9us, wall 163.3) + the
// numerically-free 12-MFMA trim. Session ledger: every occupancy lever is
// two-sided-exhausted ((256,8) at any structure -> spill disaster; (256,3)
// -> 3-wave equilibrium; split kernels -> launch overhead eats the gain).
// R9's NI=4 + (256,4) moderate-spill configuration is the measured optimum;
// the only proven-safe unapplied delta is dropping Am*Km (O(2^-22), absmax
// bit-identical in R13/R14) -> 12 MFMAs per (jt,pair), -25% MFMA issue and
// slightly lower live pressure in the spilled jt-loop.
// ---------------------------------------------------------------------------
__global__ __launch_bounds__(256, 4) void fused_mfma_attn_kernel(
    const float* __restrict__ q, const float* __restrict__ v,
    const fp16* __restrict__ khi, const fp16* __restrict__ kmid,
    const float* __restrict__ w1, const float* __restrict__ b1,
    const float* __restrict__ w2, const float* __restrict__ b2,
    fp16* __restrict__ oh, fp16* __restrict__ om)
{
    const int i4 = blockIdx.x;     // query quad: i = 4*i4 + i01
    const int bh = blockIdx.y;
    const int t  = threadIdx.x;
    const int lane = t & 63, w = t >> 6;
    const int m16 = lane & 15, q4 = lane >> 4;

    __shared__ f32x2 part2[2][4][256];  // [pair][wave][j] score partials
    __shared__ f32x2 sc2[2][256];       // softmax probabilities, 2 pairs
    __shared__ float qpb_s[4][64];
    __shared__ f32x2 sbuf2[2][256];     // bitonic cross-wave exchange
    __shared__ f32x2 red_s[2][4][64];   // attn@V partials
    __shared__ f32x2 red2_s[2][4];
    __shared__ f32x2 thr_s2[2], smax_s2[2];

    const int f = w * 16 + m16;         // this lane's f (A-operand M index)
    const float* w1row = w1 + f * 192;

    // ---- build A_i fragments for 4 queries + qpb; w1 loads hoisted
    f16x8 Ah[4][2], Am[4][2];
    float qa[4] = {0.f, 0.f, 0.f, 0.f};
    const float* qbase = q + (bh * 256 + i4 * 4) * 64;
    #pragma unroll
    for (int ks = 0; ks < 2; ks++) {
        #pragma unroll
        for (int u = 0; u < 2; u++) {
            int e = ks * 32 + q4 * 8 + u * 4;
            float4 wa = *(const float4*)&w1row[e];
            float4 wb = *(const float4*)&w1row[64 + e];
            float4 wc = *(const float4*)&w1row[128 + e];
            #pragma unroll
            for (int i01 = 0; i01 < 4; i01++) {
                float4 qv = *(const float4*)&qbase[i01 * 64 + e];
                qa[i01] += wa.x * qv.x + wa.y * qv.y + wa.z * qv.z + wa.w * qv.w;
                float av[4];
                av[0] = fmaf(wc.x, qv.x, wb.x);
                av[1] = fmaf(wc.y, qv.y, wb.y);
                av[2] = fmaf(wc.z, qv.z, wb.z);
                av[3] = fmaf(wc.w, qv.w, wb.w);
                #pragma unroll
                for (int uu = 0; uu < 4; uu++) {
                    fp16 h, m;
                    split2(av[uu], h, m);
                    Ah[i01][ks][u * 4 + uu] = h;
                    Am[i01][ks][u * 4 + uu] = m;
                }
            }
        }
    }
    #pragma unroll
    for (int i01 = 0; i01 < 4; i01++) {
        float qaa = qa[i01];
        qaa += __shfl_xor(qaa, 16);
        qaa += __shfl_xor(qaa, 32);
        if (lane < 16) qpb_s[i01][w * 16 + lane] = qaa + b1[w * 16 + lane];
    }
    __syncthreads();

    floatx4 qpbr[4];
    #pragma unroll
    for (int i01 = 0; i01 < 4; i01++)
        qpbr[i01] = *(const floatx4*)&qpb_s[i01][w * 16 + q4 * 4];
    const float4 w2f = *(const float4*)&w2[w * 16 + q4 * 4];
    const float b2v = b2[0];

    // ---- main loop: K loaded in-loop (TLP covers), 12 MFMAs per pair
    #pragma unroll 1
    for (int jt = 0; jt < 16; jt++) {
        int base = ((bh * 16 + jt) * 2 * 64 + lane) * 8;
        f16x8 Kh0 = *(const f16x8*)&khi [base];
        f16x8 Km0 = *(const f16x8*)&kmid[base];
        f16x8 Kh1 = *(const f16x8*)&khi [base + 512];
        f16x8 Km1 = *(const f16x8*)&kmid[base + 512];
        #pragma unroll
        for (int p = 0; p < 2; p++) {
            const int ia = 2 * p, ib = 2 * p + 1;
            floatx4 a0 = qpbr[ia], a1 = qpbr[ib];
            floatx4 b0, b1v_;
            b0[0] = 0.f; b0[1] = 0.f; b0[2] = 0.f; b0[3] = 0.f;
            b1v_ = b0;
            // 12 MFMAs: per query a-chain {hh0,mh0,hh1,mh1}, b-chain {hm0,hm1}
            a0   = __builtin_amdgcn_mfma_f32_16x16x32_f16(Ah[ia][0], Kh0, a0,   0, 0, 0);
            a1   = __builtin_amdgcn_mfma_f32_16x16x32_f16(Ah[ib][0], Kh0, a1,   0, 0, 0);
            b0   = __builtin_amdgcn_mfma_f32_16x16x32_f16(Ah[ia][0], Km0, b0,   0, 0, 0);
            b1v_ = __builtin_amdgcn_mfma_f32_16x16x32_f16(Ah[ib][0], Km0, b1v_, 0, 0, 0);
            a0   = __builtin_amdgcn_mfma_f32_16x16x32_f16(Am[ia][0], Kh0, a0,   0, 0, 0);
            a1   = __builtin_amdgcn_mfma_f32_16x16x32_f16(Am[ib][0], Kh0, a1,   0, 0, 0);
            b0   = __builtin_amdgcn_mfma_f32_16x16x32_f16(Ah[ia][1], Km1, b0,   0, 0, 0);
            b1v_ = __builtin_amdgcn_mfma_f32_16x16x32_f16(Ah[ib][1], Km1, b1v_, 0, 0, 0);
            a0   = __builtin_amdgcn_mfma_f32_16x16x32_f16(Ah[ia][1], Kh1, a0,   0, 0, 0);
            a1   = __builtin_amdgcn_mfma_f32_16x16x32_f16(Ah[ib][1], Kh1, a1,   0, 0, 0);
            a0   = __builtin_amdgcn_mfma_f32_16x16x32_f16(Am[ia][1], Kh1, a0,   0, 0, 0);
            a1   = __builtin_amdgcn_mfma_f32_16x16x32_f16(Am[ib][1], Kh1, a1,   0, 0, 0);
            a0 = a0 + b0; a1 = a1 + b1v_;
            // packed epilogue on (ia,ib) pair
            f32x2 g0 = gelu2(mk2(a0[0], a1[0]));
            f32x2 g1 = gelu2(mk2(a0[1], a1[1]));
            f32x2 g2 = gelu2(mk2(a0[2], a1[2]));
            f32x2 g3 = gelu2(mk2(a0[3], a1[3]));
            f32x2 sA = __builtin_elementwise_fma(g1, sp2(w2f.y), g0 * w2f.x);
            f32x2 sB = __builtin_elementwise_fma(g3, sp2(w2f.w), g2 * w2f.z);
            f32x2 s = sA + sB;
            s.x += __shfl_xor(s.x, 16);
            s.y += __shfl_xor(s.y, 16);
            s.x += __shfl_xor(s.x, 32);
            s.y += __shfl_xor(s.y, 32);
            if (lane < 16) part2[p][w][jt * 16 + lane] = s;
        }
    }
    __syncthreads();

    // ---- scores (two packed pairs = 4 queries)
    f32x2 score0 = ((part2[0][0][t] + part2[0][1][t]) +
                    (part2[0][2][t] + part2[0][3][t]) + b2v) * 0.125f;
    f32x2 score1 = ((part2[1][0][t] + part2[1][1][t]) +
                    (part2[1][2][t] + part2[1][3][t]) + b2v) * 0.125f;

    // ---- quad lockstep 256-wide bitonic sort; sorted[192] = 64th largest.
    f32x2 sv0 = score0, sv1 = score1;
    #pragma unroll
    for (int k = 2; k <= 256; k <<= 1) {
        #pragma unroll
        for (int j = k >> 1; j >= 1; j >>= 1) {
            f32x2 pv0, pv1;
            if (j >= 64) {
                sbuf2[0][t] = sv0; sbuf2[1][t] = sv1;
                __syncthreads();
                pv0 = sbuf2[0][t ^ j]; pv1 = sbuf2[1][t ^ j];
                __syncthreads();
            } else {
                pv0.x = __shfl_xor(sv0.x, j);
                pv0.y = __shfl_xor(sv0.y, j);
                pv1.x = __shfl_xor(sv1.x, j);
                pv1.y = __shfl_xor(sv1.y, j);
            }
            bool keepMin = (((t & j) == 0) == ((t & k) == 0));
            f32x2 mn0 = __builtin_elementwise_min(sv0, pv0);
            f32x2 mx0 = __builtin_elementwise_max(sv0, pv0);
            f32x2 mn1 = __builtin_elementwise_min(sv1, pv1);
            f32x2 mx1 = __builtin_elementwise_max(sv1, pv1);
            sv0 = keepMin ? mn0 : mx0;
            sv1 = keepMin ? mn1 : mx1;
        }
    }
    if (t == 192) { thr_s2[0]  = sv0; thr_s2[1]  = sv1; }
    if (t == 255) { smax_s2[0] = sv0; smax_s2[1] = sv1; }
    __syncthreads();

    // ---- softmax numerator + denominator (two packed pairs)
    float p00 = (score0.x >= thr_s2[0].x) ? __expf(score0.x - smax_s2[0].x) : 0.0f;
    float p01 = (score0.y >= thr_s2[0].y) ? __expf(score0.y - smax_s2[0].y) : 0.0f;
    float p10 = (score1.x >= thr_s2[1].x) ? __expf(score1.x - smax_s2[1].x) : 0.0f;
    float p11 = (score1.y >= thr_s2[1].y) ? __expf(score1.y - smax_s2[1].y) : 0.0f;
    sc2[0][t] = mk2(p00, p01);
    sc2[1][t] = mk2(p10, p11);
    f32x2 ps0 = mk2(p00, p01), ps1 = mk2(p10, p11);
    #pragma unroll
    for (int mask = 1; mask < 64; mask <<= 1) {
        ps0.x += __shfl_xor(ps0.x, mask);
        ps0.y += __shfl_xor(ps0.y, mask);
        ps1.x += __shfl_xor(ps1.x, mask);
        ps1.y += __shfl_xor(ps1.y, mask);
    }
    if (lane == 0) { red2_s[0][w] = ps0; red2_s[1][w] = ps1; }
    __syncthreads();
    f32x2 den0 = (red2_s[0][0] + red2_s[0][1]) + (red2_s[0][2] + red2_s[0][3]);
    f32x2 den1 = (red2_s[1][0] + red2_s[1][1]) + (red2_s[1][2] + red2_s[1][3]);
    f32x2 invp0 = mk2(1.0f / den0.x, 1.0f / den0.y);
    f32x2 invp1 = mk2(1.0f / den1.x, 1.0f / den1.y);

    // ---- attn @ V: V loads shared across all 4 queries, x2 unroll
    const int d = t & 63, g = t >> 6;
    const float* vb = v + bh * 256 * 64;
    f32x2 av0 = mk2(0.f, 0.f), av1 = mk2(0.f, 0.f);
    f32x2 av0b = mk2(0.f, 0.f), av1b = mk2(0.f, 0.f);
    for (int j8 = 0; j8 < 8; j8++) {
        int jj = g * 64 + j8 * 8;
        float v0 = vb[(jj + 0) * 64 + d];
        float v1 = vb[(jj + 1) * 64 + d];
        float v2 = vb[(jj + 2) * 64 + d];
        float v3 = vb[(jj + 3) * 64 + d];
        float v4 = vb[(jj + 4) * 64 + d];
        float v5 = vb[(jj + 5) * 64 + d];
        float v6 = vb[(jj + 6) * 64 + d];
        float v7 = vb[(jj + 7) * 64 + d];
        av0  = __builtin_elementwise_fma(sc2[0][jj + 0], sp2(v0), av0);
        av1  = __builtin_elementwise_fma(sc2[1][jj + 0], sp2(v0), av1);
        av0b = __builtin_elementwise_fma(sc2[0][jj + 4], sp2(v4), av0b);
        av1b = __builtin_elementwise_fma(sc2[1][jj + 4], sp2(v4), av1b);
        av0  = __builtin_elementwise_fma(sc2[0][jj + 1], sp2(v1), av0);
        av1  = __builtin_elementwise_fma(sc2[1][jj + 1], sp2(v1), av1);
        av0b = __builtin_elementwise_fma(sc2[0][jj + 5], sp2(v5), av0b);
        av1b = __builtin_elementwise_fma(sc2[1][jj + 5], sp2(v5), av1b);
        av0  = __builtin_elementwise_fma(sc2[0][jj + 2], sp2(v2), av0);
        av1  = __builtin_elementwise_fma(sc2[1][jj + 2], sp2(v2), av1);
        av0b = __builtin_elementwise_fma(sc2[0][jj + 6], sp2(v6), av0b);
        av1b = __builtin_elementwise_fma(sc2[1][jj + 6], sp2(v6), av1b);
        av0  = __builtin_elementwise_fma(sc2[0][jj + 3], sp2(v3), av0);
        av1  = __builtin_elementwise_fma(sc2[1][jj + 3], sp2(v3), av1);
        av0b = __builtin_elementwise_fma(sc2[0][jj + 7], sp2(v7), av0b);
        av1b = __builtin_elementwise_fma(sc2[1][jj + 7], sp2(v7), av1b);
    }
    red_s[0][g][d] = av0 + av0b;
    red_s[1][g][d] = av1 + av1b;
    __syncthreads();

    // ---- output: all 256 threads write one (i01, dd) each
    {
        int i01 = t >> 6, dd = t & 63;
        int pr = i01 >> 1, comp = i01 & 1;
        f32x2 osum = (red_s[pr][0][dd] + red_s[pr][1][dd]) +
                     (red_s[pr][2][dd] + red_s[pr][3][dd]);
        f32x2 iv = pr ? invp1 : invp0;
        float o = (comp ? osum.y : osum.x) * (comp ? iv.y : iv.x);
        int b = bh >> 3, h = bh & 7;
        int row = b * 256 + i4 * 4 + i01;
        int n = h * 64 + dd;
        int dst = (((row >> 4) * 16 + (n >> 5)) * 64 + ((n >> 3) & 3) * 16 + (row & 15)) * 8 + (n & 7);
        fp16 hh, mm;
        split2(o, hh, mm);
        oh[dst] = hh; om[dst] = mm;
    }
}

// ---------------------------------------------------------------------------
extern "C" void kernel_launch(void* const* d_in, const int* in_sizes, int n_in,
                              void* d_out, int out_size, void* d_ws, size_t ws_size,
                              hipStream_t stream) {
    const float* x  = (const float*)d_in[0];
    const float* Wq = (const float*)d_in[1];
    const float* bq = (const float*)d_in[2];
    const float* Wk = (const float*)d_in[3];
    const float* bk = (const float*)d_in[4];
    const float* Wv = (const float*)d_in[5];
    const float* bv = (const float*)d_in[6];
    const float* w1 = (const float*)d_in[7];
    const float* b1 = (const float*)d_in[8];
    const float* w2 = (const float*)d_in[9];
    const float* b2 = (const float*)d_in[10];
    const float* Wo = (const float*)d_in[11];
    const float* bo = (const float*)d_in[12];
    float* out = (float*)d_out;

    const int NE = 262144;   // 512*512
    float* qb  = (float*)d_ws;          // q (b,h,c,d) fp32
    float* vb  = qb + NE;               // v (b,h,c,d) fp32
    fp16* base = (fp16*)(vb + NE);
    fp16* khi  = base;            fp16* kmid = khi + NE;
    fp16* xs   = kmid + NE;       // hi/mid duals follow (2*NE each)
    fp16* wqs  = xs  + 2 * NE;
    fp16* wks  = wqs + 2 * NE;
    fp16* wvs  = wks + 2 * NE;
    fp16* wos  = wvs + 2 * NE;
    fp16* oas  = wos + 2 * NE;

    // 1) split x, Wq, Wk, Wv, Wo into frag-major fp16 duals
    {
        SplitArgs S;
        const float* srcs[5] = {x, Wq, Wk, Wv, Wo};
        fp16* dsts[5] = {xs, wqs, wks, wvs, wos};
        for (int z = 0; z < 5; z++) {
            S.src[z] = srcs[z];
            S.h[z] = dsts[z]; S.m[z] = dsts[z] + NE;
        }
        split2_512_kernel<<<dim3(256, 1, 5), 256, 0, stream>>>(S);
    }
    // 2) QKV projections; K written directly as dual-split frag-major
    {
        MM2Args M;
        M.Ah = xs; M.Am = xs + NE;
        M.Wh[0] = wqs; M.Wm[0] = wqs + NE;
        M.Wh[1] = wks; M.Wm[1] = wks + NE;
        M.Wh[2] = wvs; M.Wm[2] = wvs + NE;
        M.bias[0] = bq; M.bias[1] = bk; M.bias[2] = bv;
        M.outf[0] = qb; M.outf[1] = nullptr; M.outf[2] = vb;
        M.kh = khi; M.km = kmid;
        M.mode[0] = 1; M.mode[1] = 2; M.mode[2] = 1;
        mm_mfma_kernel<<<dim3(32, 32, 3), 64, 0, stream>>>(M);
    }
    // 3) fused second-order scores + top-64 + softmax + attn@V (+ dual out)
    fused_mfma_attn_kernel<<<dim3(64, 16), 256, 0, stream>>>(
        qb, vb, khi, kmid, w1, b1, w2, b2,
        oas, oas + NE);
    // 4) output projection
    {
        MM2Args M;
        M.Ah = oas; M.Am = oas + NE;
        M.Wh[0] = wos; M.Wm[0] = wos + NE;
        M.Wh[1] = wos; M.Wm[1] = wos;
        M.Wh[2] = wos; M.Wm[2] = wos;
        M.bias[0] = bo; M.bias[1] = bo; M.bias[2] = bo;
        M.outf[0] = out; M.outf[1] = out; M.outf[2] = out;
        M.kh = khi; M.km = kmid;
        M.mode[0] = 0; M.mode[1] = 0; M.mode[2] = 0;
        mm_mfma_kernel<<<dim3(32, 32, 1), 64, 0, stream>>>(M);
    }
}